// Round 13
// baseline (571.417 us; speedup 1.0000x reference)
//
#include <hip/hip_runtime.h>
#include <hip/hip_fp16.h>
#include <math.h>

#define N 8192
#define D 512
#define KSEL 20
#define CAND_CAP 320
#define ROWU 8192
#define FS_A 4096

typedef __attribute__((ext_vector_type(8))) short short8;
typedef __attribute__((ext_vector_type(4))) float f32x4;

__device__ __forceinline__ unsigned short f2bf(float x) {
  unsigned int u = __float_as_uint(x);
  unsigned int r = u + 0x7FFFu + ((u >> 16) & 1u);
  return (unsigned short)(r >> 16);
}

__device__ __forceinline__ unsigned int packh2(float a, float b) {
  return (unsigned int)__half_as_ushort(__float2half(a)) |
         ((unsigned int)__half_as_ushort(__float2half(b)) << 16);
}

__device__ __forceinline__ void gld16(const unsigned short* g, unsigned short* l) {
  __builtin_amdgcn_global_load_lds(
      (const __attribute__((address_space(1))) unsigned int*)g,
      (__attribute__((address_space(3))) unsigned int*)l, 16, 0, 0);
}

__device__ __forceinline__ int swz(int row, int cp) {
  return row * 64 + ((((cp >> 2) ^ (row & 15)) << 2) | (cp & 3));
}
__device__ __forceinline__ int swz4(int row, int q) {
  return row * 64 + ((q ^ (row & 15)) << 2);
}

// ---------------------------------------------------------------------------
// K1: fused np-exact prep + fnorm (FROZEN arithmetic — verified R9..R12).
// RESTRUCTURED for TLP: one row per wave, grid N/4 (was 256 blocks = 1/CU).
// ---------------------------------------------------------------------------
__global__ __launch_bounds__(256) void prep_kernel(
    const float* __restrict__ feat, const float* __restrict__ pos,
    const float* __restrict__ lamw,
    float* __restrict__ normf, float* __restrict__ sqf,
    float* __restrict__ fn32, unsigned short* __restrict__ fnbf,
    float* __restrict__ out) {
  __shared__ float rowbuf[4][512];
  int w = threadIdx.x >> 6, lane = threadIdx.x & 63;
  float* rb = rowbuf[w];
  int row = blockIdx.x * 4 + w;
  const float* f = feat + (size_t)row * D;
  float4 v0 = *(const float4*)(f + 4 * lane);
  float4 v1 = *(const float4*)(f + 256 + 4 * lane);
  *(float4*)&rb[4 * lane] = v0;
  *(float4*)&rb[256 + 4 * lane] = v1;
  __builtin_amdgcn_s_waitcnt(0);             // LDS visible in-wave
  float s = 0.f;
  if (lane < 32) {
    int b = lane >> 3, j = lane & 7;
    const float* a = rb + b * 128 + j;
    float r = __fmul_rn(a[0], a[0]);
    #pragma unroll
    for (int k = 1; k < 16; k++)
      r = __fadd_rn(r, __fmul_rn(a[8 * k], a[8 * k]));
    r = __fadd_rn(r, __shfl_xor(r, 1, 64));
    r = __fadd_rn(r, __shfl_xor(r, 2, 64));
    r = __fadd_rn(r, __shfl_xor(r, 4, 64));
    r = __fadd_rn(r, __shfl_xor(r, 8, 64));
    r = __fadd_rn(r, __shfl_xor(r, 16, 64));   // numpy pairwise tree
    s = r;
  }
  float st = __shfl(s, 0, 64);
  float nrm = fmaxf(__fsqrt_rn(st), 1e-12f);
  if (lane == 0) {
    normf[row] = nrm;
    float x = pos[2 * row], y = pos[2 * row + 1];
    sqf[row] = __fadd_rn(__fmul_rn(x, x), __fmul_rn(y, y));
    if (row == 0) {
      float e = (float)exp(-(double)lamw[0]);
      out[(size_t)N * N] = 1.0f / __fadd_rn(1.0f, e);
    }
  }
  float4 q0, q1;
  q0.x = v0.x / nrm; q0.y = v0.y / nrm; q0.z = v0.z / nrm; q0.w = v0.w / nrm;
  q1.x = v1.x / nrm; q1.y = v1.y / nrm; q1.z = v1.z / nrm; q1.w = v1.w / nrm;
  *(float4*)(fn32 + (size_t)row * D + 4 * lane) = q0;
  *(float4*)(fn32 + (size_t)row * D + 256 + 4 * lane) = q1;
  uint2 o0, o1;
  o0.x = (unsigned int)f2bf(q0.x) | ((unsigned int)f2bf(q0.y) << 16);
  o0.y = (unsigned int)f2bf(q0.z) | ((unsigned int)f2bf(q0.w) << 16);
  o1.x = (unsigned int)f2bf(q1.x) | ((unsigned int)f2bf(q1.y) << 16);
  o1.y = (unsigned int)f2bf(q1.z) | ((unsigned int)f2bf(q1.w) << 16);
  *(uint2*)(fnbf + (size_t)row * D + 4 * lane) = o0;
  *(uint2*)(fnbf + (size_t)row * D + 256 + 4 * lane) = o1;
}

// ---------------------------------------------------------------------------
// K2: symmetric bf16-MFMA filter, interleaved zero-stripe (unchanged R12).
// ---------------------------------------------------------------------------
__global__ __launch_bounds__(256) void adj_kernel(
    const unsigned short* __restrict__ G,
    const float* __restrict__ pos, const float* __restrict__ sqf,
    const float* __restrict__ lamw, const float* __restrict__ temp,
    unsigned int* __restrict__ filt, int fs,
    unsigned int* __restrict__ out_u, int mode) {
  __shared__ __align__(16) unsigned char smem[32768];
  unsigned short* As = (unsigned short*)smem;
  unsigned short* Bs = As + 8192;
  unsigned int* tileT = (unsigned int*)smem;

  int L = blockIdx.x;
  int tid = threadIdx.x;

  int by = (int)((129.0 - sqrt(129.0 * 129.0 - 8.0 * (double)L)) * 0.5);
  while (64 * (by + 1) - ((by + 1) * by) / 2 <= L) by++;
  while (64 * by - (by * (by - 1)) / 2 > L) by--;
  int bx = by + (L - (64 * by - (by * (by - 1)) / 2));

  int wave = tid >> 6, lane = tid & 63;
  int wr = (wave >> 1) * 64, wc = (wave & 1) * 64;
  int m = lane & 15, quad = lane >> 4;

  f32x4 acc[4][4];
  #pragma unroll
  for (int i = 0; i < 4; i++)
    #pragma unroll
    for (int j = 0; j < 4; j++) acc[i][j] = (f32x4){0.f, 0.f, 0.f, 0.f};

  for (int kt = 0; kt < D / 64; kt++) {
    #pragma unroll
    for (int i = 0; i < 4; i++) {
      int f = i * 256 + tid;
      int r = f >> 3, c = f & 7;
      int cs = (c + r) & 7;
      size_t goff = (size_t)r * D + kt * 64 + cs * 8;
      gld16(G + (size_t)(by * 128) * D + goff, &As[f * 8]);
      gld16(G + (size_t)(bx * 128) * D + goff, &Bs[f * 8]);
    }
    if (L < 2048) {
      uint4 z = {0u, 0u, 0u, 0u};
      if (mode == 0) {
        size_t base = (size_t)L * 32768 + (size_t)kt * 4096;
        #pragma unroll
        for (int it2 = 0; it2 < 4; it2++)
          *(uint4*)(out_u + base + it2 * 1024 + tid * 4) = z;
      } else {
        #pragma unroll
        for (int it2 = 0; it2 < 2; it2++) {
          int g = L * 16384 + (kt * 2 + it2) * 1024 + tid * 4;
          int r = g >> 12, c = g & 4095;
          *(uint4*)(out_u + (size_t)r * ROWU + 4096 + c) = z;
        }
      }
    }
    __syncthreads();
    #pragma unroll
    for (int h = 0; h < 2; h++) {
      short8 fa[4], fb[4];
      #pragma unroll
      for (int ti = 0; ti < 4; ti++) {
        int row = wr + ti * 16 + m;
        int cc = ((h * 4 + quad) - row) & 7;
        fa[ti] = *(const short8*)&As[row * 64 + cc * 8];
      }
      #pragma unroll
      for (int tj = 0; tj < 4; tj++) {
        int row = wc + tj * 16 + m;
        int cc = ((h * 4 + quad) - row) & 7;
        fb[tj] = *(const short8*)&Bs[row * 64 + cc * 8];
      }
      #pragma unroll
      for (int ti = 0; ti < 4; ti++)
        #pragma unroll
        for (int tj = 0; tj < 4; tj++)
          acc[ti][tj] = __builtin_amdgcn_mfma_f32_16x16x32_bf16(
              fa[ti], fb[tj], acc[ti][tj], 0, 0, 0);
    }
    __syncthreads();
  }

  float lam = 1.f / (1.f + __expf(-lamw[0]));
  float T = temp[0];
  float oml = 1.f - lam;
  bool offdiag = (bx != by);

  #pragma unroll
  for (int ti = 0; ti < 4; ti++) {
    int gi0 = by * 128 + wr + ti * 16 + quad * 4;
    float xi[4], yi[4], sqi[4];
    #pragma unroll
    for (int r = 0; r < 4; r++) {
      int gi = gi0 + r;
      xi[r] = pos[2 * gi]; yi[r] = pos[2 * gi + 1]; sqi[r] = sqf[gi];
    }
    #pragma unroll
    for (int tj = 0; tj < 4; tj++) {
      int gj = bx * 128 + wc + tj * 16 + m;
      float xj = pos[2 * gj], yj = pos[2 * gj + 1], sj = sqf[gj];
      f32x4 c = acc[ti][tj];
      float sv[4];
      #pragma unroll
      for (int r = 0; r < 4; r++) {
        float d2 = fmaxf(sqi[r] + sj - 2.f * (xi[r] * xj + yi[r] * yj), 0.f);
        float sp = __expf(-d2 * (1.f / 5000.f));
        sv[r] = (lam * c[r] + oml * sp) * T;
      }
      int cpL = (wc + tj * 16 + m) >> 1;
      #pragma unroll
      for (int r = 0; r < 4; r++) {
        float pv = __shfl_xor(sv[r], 1, 64);
        if (!(lane & 1)) {
          int rowL = wr + ti * 16 + quad * 4 + r;
          tileT[swz(rowL, cpL)] = packh2(sv[r], pv);
        }
      }
    }
  }
  __syncthreads();

  #pragma unroll
  for (int it = 0; it < 8; it++) {
    int idx4 = it * 256 + tid;
    int row = idx4 >> 4, q = idx4 & 15;
    uint4 v = *(uint4*)&tileT[swz4(row, q)];
    *(uint4*)(filt + (size_t)(by * 128 + row) * fs + bx * 64 + q * 4) = v;
  }

  if (offdiag) {
    #pragma unroll
    for (int it = 0; it < 8; it++) {
      int idx4 = it * 256 + tid;
      int c = idx4 >> 4, q = idx4 & 15;
      unsigned int wv[4];
      #pragma unroll
      for (int d = 0; d < 4; d++) {
        int p = q * 4 + d;
        unsigned int lo = tileT[swz(2 * p, c >> 1)];
        unsigned int hi = tileT[swz(2 * p + 1, c >> 1)];
        unsigned int h0 = (c & 1) ? (lo >> 16) : (lo & 0xFFFFu);
        unsigned int h1 = (c & 1) ? (hi >> 16) : (hi & 0xFFFFu);
        wv[d] = h0 | (h1 << 16);
      }
      uint4 v; v.x = wv[0]; v.y = wv[1]; v.z = wv[2]; v.w = wv[3];
      *(uint4*)(filt + (size_t)(bx * 128 + c) * fs + by * 64 + q * 4) = v;
    }
  }
}

// ---------------------------------------------------------------------------
// K3: TWO rows per block (grid N/2). Packed-fp16 bsearch with dual
// independent chains (4-way split accumulators), shared barriers; parallel
// selection on waves 0/1. np-exact recompute + selection FROZEN.
// ---------------------------------------------------------------------------
__global__ __launch_bounds__(256, 4) void topk_kernel(
    const float* __restrict__ pos, const float* __restrict__ sqf,
    const float* __restrict__ lamw, const float* __restrict__ temp,
    const float* __restrict__ fn32,
    const unsigned int* __restrict__ filt, int fs,
    float* __restrict__ out, int doZero) {
  __shared__ float ai[2][D];
  __shared__ int   redi[2][4][2];
  __shared__ int   candIdx[2][CAND_CAP];
  __shared__ float candV[2][CAND_CAP];
  __shared__ int   selIdx[2][KSEL];
  __shared__ float selVal[2][KSEL];
  __shared__ int   cnt[2];

  int t = threadIdx.x;
  int lane = t & 63, wid = t >> 6;
  int row0 = blockIdx.x * 2, row1 = row0 + 1;
  float* orow0 = out + (size_t)row0 * N;
  float* orow1 = out + (size_t)row1 * N;
  const uint4* fu0 = (const uint4*)(filt + (size_t)row0 * fs);
  const uint4* fu1 = (const uint4*)(filt + (size_t)row1 * fs);

  unsigned int rv0[16], rv1[16];
  #pragma unroll
  for (int q = 0; q < 4; q++) {
    uint4 u0 = fu0[t + 256 * q];
    uint4 u1 = fu1[t + 256 * q];
    rv0[4 * q] = u0.x; rv0[4 * q + 1] = u0.y; rv0[4 * q + 2] = u0.z; rv0[4 * q + 3] = u0.w;
    rv1[4 * q] = u1.x; rv1[4 * q + 1] = u1.y; rv1[4 * q + 2] = u1.z; rv1[4 * q + 3] = u1.w;
  }
  for (int k = t; k < D; k += 256) {
    ai[0][k] = fn32[(size_t)row0 * D + k];   // np-exact a_i
    ai[1][k] = fn32[(size_t)row1 * D + k];
  }
  if (t < 2) cnt[t] = 0;
  __syncthreads();

  if (doZero) {
    float4 z4 = {0.f, 0.f, 0.f, 0.f};
    #pragma unroll
    for (int i = 0; i < 4; i++) *(float4*)&orow0[4 * t + 1024 * i] = z4;
    #pragma unroll
    for (int i = 0; i < 4; i++) *(float4*)&orow1[4 * t + 1024 * i] = z4;
  }

  // --- dual packed binary search: 12 iters on [-1, 1.5] ---
  float lo0 = -1.0f, hi0 = 1.5f, lo1 = -1.0f, hi1 = 1.5f;
  for (int it = 0; it < 12; it++) {
    float mid0 = 0.5f * (lo0 + hi0);
    float mid1 = 0.5f * (lo1 + hi1);
    __half2 m20 = __float2half2_rn(mid0);
    __half2 m21 = __float2half2_rn(mid1);
    __half2 p[4] = {__float2half2_rn(0.f), __float2half2_rn(0.f),
                    __float2half2_rn(0.f), __float2half2_rn(0.f)};
    __half2 qd[4] = {__float2half2_rn(0.f), __float2half2_rn(0.f),
                     __float2half2_rn(0.f), __float2half2_rn(0.f)};
    #pragma unroll
    for (int r = 0; r < 16; r++) {
      p[r & 3]  = __hadd2(p[r & 3],  __hge2(*(__half2*)&rv0[r], m20));
      qd[r & 3] = __hadd2(qd[r & 3], __hge2(*(__half2*)&rv1[r], m21));
    }
    __half2 pc = __hadd2(__hadd2(p[0], p[1]), __hadd2(p[2], p[3]));
    __half2 qc = __hadd2(__hadd2(qd[0], qd[1]), __hadd2(qd[2], qd[3]));
    int c0 = (int)(__low2float(pc) + __high2float(pc));
    int c1 = (int)(__low2float(qc) + __high2float(qc));
    #pragma unroll
    for (int off = 32; off > 0; off >>= 1) {
      c0 += __shfl_down(c0, off, 64);
      c1 += __shfl_down(c1, off, 64);
    }
    if (lane == 0) { redi[it & 1][wid][0] = c0; redi[it & 1][wid][1] = c1; }
    __syncthreads();
    int tot0 = redi[it & 1][0][0] + redi[it & 1][1][0] + redi[it & 1][2][0] + redi[it & 1][3][0];
    int tot1 = redi[it & 1][0][1] + redi[it & 1][1][1] + redi[it & 1][2][1] + redi[it & 1][3][1];
    if (tot0 >= KSEL) lo0 = mid0; else hi0 = mid0;
    if (tot1 >= KSEL) lo1 = mid1; else hi1 = mid1;
  }

  // --- packed candidate sweep (R11/R12-proven margins) ---
  __half2 t20 = __float2half2_rn(lo0 - 3.7e-3f - 6e-4f);
  __half2 t21 = __float2half2_rn(lo1 - 3.7e-3f - 6e-4f);
  #pragma unroll
  for (int r = 0; r < 16; r++) {
    __half2 ge0 = __hge2(*(__half2*)&rv0[r], t20);
    __half2 ge1 = __hge2(*(__half2*)&rv1[r], t21);
    unsigned int g0 = *(unsigned int*)&ge0;
    unsigned int g1 = *(unsigned int*)&ge1;
    int j0 = 8 * (t + 256 * (r >> 2)) + 2 * (r & 3);
    if (g0) {
      if (g0 & 0xFFFFu) {
        int p = atomicAdd(&cnt[0], 1);
        if (p < CAND_CAP) candIdx[0][p] = j0;
      }
      if (g0 >> 16) {
        int p = atomicAdd(&cnt[0], 1);
        if (p < CAND_CAP) candIdx[0][p] = j0 + 1;
      }
    }
    if (g1) {
      if (g1 & 0xFFFFu) {
        int p = atomicAdd(&cnt[1], 1);
        if (p < CAND_CAP) candIdx[1][p] = j0;
      }
      if (g1 >> 16) {
        int p = atomicAdd(&cnt[1], 1);
        if (p < CAND_CAP) candIdx[1][p] = j0 + 1;
      }
    }
  }
  __syncthreads();
  int n0 = min(cnt[0], CAND_CAP), n1 = min(cnt[1], CAND_CAP);
  int ntot = n0 + n1;

  // --- per-thread streamed np-exact recompute (FROZEN arithmetic) ---
  float lamf;
  { float e = (float)exp(-(double)lamw[0]); lamf = 1.0f / __fadd_rn(1.0f, e); }
  float omlf = __fadd_rn(1.0f, -lamf);
  float Tf = temp[0];
  float sq_i2[2] = {sqf[row0], sqf[row1]};
  float xi2[2] = {pos[2 * row0], pos[2 * row1]};
  float yi2[2] = {pos[2 * row0 + 1], pos[2 * row1 + 1]};

  for (int ci = t; ci < ntot; ci += 256) {
    int rsel = (ci >= n0) ? 1 : 0;
    int idx = rsel ? (ci - n0) : ci;
    int j = candIdx[rsel][idx];
    const float* fj = fn32 + (size_t)j * D;
    float accv = 0.0f;
    float4 buf[4], nxt[4];
    #pragma unroll
    for (int q = 0; q < 4; q++) buf[q] = *(const float4*)(fj + q * 4);
    for (int c16 = 0; c16 < 32; c16++) {
      if (c16 < 31) {
        #pragma unroll
        for (int q = 0; q < 4; q++)
          nxt[q] = *(const float4*)(fj + (c16 + 1) * 16 + q * 4);
      }
      #pragma unroll
      for (int q = 0; q < 4; q++) {
        float4 a4 = *(const float4*)&ai[rsel][c16 * 16 + q * 4];
        accv = __fmaf_rn(a4.x, buf[q].x, accv);   // frozen k-order
        accv = __fmaf_rn(a4.y, buf[q].y, accv);
        accv = __fmaf_rn(a4.z, buf[q].z, accv);
        accv = __fmaf_rn(a4.w, buf[q].w, accv);
      }
      #pragma unroll
      for (int q = 0; q < 4; q++) buf[q] = nxt[q];
    }
    float xj = pos[2 * j], yj = pos[2 * j + 1];
    float dot2 = __fmaf_rn(yi2[rsel], yj, __fmul_rn(xi2[rsel], xj));
    float Ssum = __fadd_rn(sq_i2[rsel], sqf[j]);
    float d2 = fmaxf(__fadd_rn(Ssum, -__fmul_rn(2.0f, dot2)), 0.0f);
    float arg = (-d2) / 5000.0f;
    float sp = (float)exp((double)arg);
    float u = __fmul_rn(__fadd_rn(__fmul_rn(lamf, accv), __fmul_rn(omlf, sp)), Tf);
    float e = (float)exp(-(double)u);
    candV[rsel][idx] = 1.0f / __fadd_rn(1.0f, e);
  }
  __syncthreads();

  // --- selection: wave0 -> row0, wave1 -> row1 (parallel, wave-local) ---
  if (wid < 2) {
    int rsel = wid;
    int nc = rsel ? n1 : n0;
    for (int s = 0; s < KSEL; s++) {
      float bu = -1.0f; int bj = N, bs = 0;
      for (int c = lane; c < nc; c += 64) {
        float v = candV[rsel][c]; int j = candIdx[rsel][c];
        if (v > bu || (v == bu && j < bj)) { bu = v; bj = j; bs = c; }
      }
      #pragma unroll
      for (int off = 32; off > 0; off >>= 1) {
        float ov = __shfl_down(bu, off, 64);
        int   oj = __shfl_down(bj, off, 64);
        int   os = __shfl_down(bs, off, 64);
        if (ov > bu || (ov == bu && oj < bj)) { bu = ov; bj = oj; bs = os; }
      }
      if (lane == 0) { selIdx[rsel][s] = bj; selVal[rsel][s] = bu; candV[rsel][bs] = -1.0f; }
      __builtin_amdgcn_s_waitcnt(0);
    }
  }
  __syncthreads();
  if (t < KSEL) orow0[selIdx[0][t]] = selVal[0][t];
  else if (t >= 64 && t < 64 + KSEL) orow1[selIdx[1][t - 64]] = selVal[1][t - 64];
}

extern "C" void kernel_launch(void* const* d_in, const int* in_sizes, int n_in,
                              void* d_out, int out_size, void* d_ws, size_t ws_size,
                              hipStream_t stream) {
  const float* feat = (const float*)d_in[0];
  const float* pos  = (const float*)d_in[1];
  const float* lamw = (const float*)d_in[2];
  const float* temp = (const float*)d_in[3];
  float* out = (float*)d_out;
  unsigned int* out_u = (unsigned int*)d_out;

  float* normf = (float*)d_ws;
  float* sqf   = normf + N;
  float* fn32  = sqf + N;
  unsigned short* fnbf = (unsigned short*)(fn32 + (size_t)N * D);
  unsigned int* filtA = (unsigned int*)(fnbf + (size_t)N * D);
  size_t needA = (size_t)2 * N * 4 + (size_t)N * D * 4 + (size_t)N * D * 2 +
                 (size_t)N * FS_A * 4;

  prep_kernel<<<N / 4, 256, 0, stream>>>(feat, pos, lamw, normf, sqf,
                                         fn32, fnbf, out);
  if (ws_size >= needA) {
    adj_kernel<<<2080, 256, 0, stream>>>(fnbf, pos, sqf, lamw, temp,
                                         filtA, FS_A, out_u, 0);
    topk_kernel<<<N / 2, 256, 0, stream>>>(pos, sqf, lamw, temp, fn32,
                                           filtA, FS_A, out, 0);
  } else {
    adj_kernel<<<2080, 256, 0, stream>>>(fnbf, pos, sqf, lamw, temp,
                                         out_u, ROWU, out_u, 1);
    topk_kernel<<<N / 2, 256, 0, stream>>>(pos, sqf, lamw, temp, fn32,
                                           out_u, ROWU, out, 1);
  }
}

// Round 14
// 555.840 us; speedup vs baseline: 1.0280x; 1.0280x over previous
//
#include <hip/hip_runtime.h>
#include <hip/hip_fp16.h>
#include <math.h>

#define N 8192
#define D 512
#define KSEL 20
#define CAND_CAP 320
#define ROWU 8192
#define FS_A 4096

typedef __attribute__((ext_vector_type(8))) short short8;
typedef __attribute__((ext_vector_type(4))) float f32x4;

__device__ __forceinline__ unsigned short f2bf(float x) {
  unsigned int u = __float_as_uint(x);
  unsigned int r = u + 0x7FFFu + ((u >> 16) & 1u);
  return (unsigned short)(r >> 16);
}

__device__ __forceinline__ unsigned int packh2(float a, float b) {
  return (unsigned int)__half_as_ushort(__float2half(a)) |
         ((unsigned int)__half_as_ushort(__float2half(b)) << 16);
}

__device__ __forceinline__ void gld16(const unsigned short* g, unsigned short* l) {
  __builtin_amdgcn_global_load_lds(
      (const __attribute__((address_space(1))) unsigned int*)g,
      (__attribute__((address_space(3))) unsigned int*)l, 16, 0, 0);
}

__device__ __forceinline__ int swz(int row, int cp) {
  return row * 64 + ((((cp >> 2) ^ (row & 15)) << 2) | (cp & 3));
}
__device__ __forceinline__ int swz4(int row, int q) {
  return row * 64 + ((q ^ (row & 15)) << 2);
}

// ---------------------------------------------------------------------------
// K1: fused np-exact prep + fnorm (FROZEN arithmetic). One row per wave,
// grid N/4 (R13 restructure — proven absmax 0.0, ~8 us faster than R12's).
// ---------------------------------------------------------------------------
__global__ __launch_bounds__(256) void prep_kernel(
    const float* __restrict__ feat, const float* __restrict__ pos,
    const float* __restrict__ lamw,
    float* __restrict__ normf, float* __restrict__ sqf,
    float* __restrict__ fn32, unsigned short* __restrict__ fnbf,
    float* __restrict__ out) {
  __shared__ float rowbuf[4][512];
  int w = threadIdx.x >> 6, lane = threadIdx.x & 63;
  float* rb = rowbuf[w];
  int row = blockIdx.x * 4 + w;
  const float* f = feat + (size_t)row * D;
  float4 v0 = *(const float4*)(f + 4 * lane);
  float4 v1 = *(const float4*)(f + 256 + 4 * lane);
  *(float4*)&rb[4 * lane] = v0;
  *(float4*)&rb[256 + 4 * lane] = v1;
  __builtin_amdgcn_s_waitcnt(0);             // LDS visible in-wave
  float s = 0.f;
  if (lane < 32) {
    int b = lane >> 3, j = lane & 7;
    const float* a = rb + b * 128 + j;
    float r = __fmul_rn(a[0], a[0]);
    #pragma unroll
    for (int k = 1; k < 16; k++)
      r = __fadd_rn(r, __fmul_rn(a[8 * k], a[8 * k]));
    r = __fadd_rn(r, __shfl_xor(r, 1, 64));
    r = __fadd_rn(r, __shfl_xor(r, 2, 64));
    r = __fadd_rn(r, __shfl_xor(r, 4, 64));
    r = __fadd_rn(r, __shfl_xor(r, 8, 64));
    r = __fadd_rn(r, __shfl_xor(r, 16, 64));   // numpy pairwise tree
    s = r;
  }
  float st = __shfl(s, 0, 64);
  float nrm = fmaxf(__fsqrt_rn(st), 1e-12f);
  if (lane == 0) {
    normf[row] = nrm;
    float x = pos[2 * row], y = pos[2 * row + 1];
    sqf[row] = __fadd_rn(__fmul_rn(x, x), __fmul_rn(y, y));
    if (row == 0) {
      float e = (float)exp(-(double)lamw[0]);
      out[(size_t)N * N] = 1.0f / __fadd_rn(1.0f, e);
    }
  }
  float4 q0, q1;
  q0.x = v0.x / nrm; q0.y = v0.y / nrm; q0.z = v0.z / nrm; q0.w = v0.w / nrm;
  q1.x = v1.x / nrm; q1.y = v1.y / nrm; q1.z = v1.z / nrm; q1.w = v1.w / nrm;
  *(float4*)(fn32 + (size_t)row * D + 4 * lane) = q0;
  *(float4*)(fn32 + (size_t)row * D + 256 + 4 * lane) = q1;
  uint2 o0, o1;
  o0.x = (unsigned int)f2bf(q0.x) | ((unsigned int)f2bf(q0.y) << 16);
  o0.y = (unsigned int)f2bf(q0.z) | ((unsigned int)f2bf(q0.w) << 16);
  o1.x = (unsigned int)f2bf(q1.x) | ((unsigned int)f2bf(q1.y) << 16);
  o1.y = (unsigned int)f2bf(q1.z) | ((unsigned int)f2bf(q1.w) << 16);
  *(uint2*)(fnbf + (size_t)row * D + 4 * lane) = o0;
  *(uint2*)(fnbf + (size_t)row * D + 256 + 4 * lane) = o1;
}

// ---------------------------------------------------------------------------
// K2: symmetric bf16-MFMA filter, interleaved zero-stripe (R12 — proven).
// ---------------------------------------------------------------------------
__global__ __launch_bounds__(256) void adj_kernel(
    const unsigned short* __restrict__ G,
    const float* __restrict__ pos, const float* __restrict__ sqf,
    const float* __restrict__ lamw, const float* __restrict__ temp,
    unsigned int* __restrict__ filt, int fs,
    unsigned int* __restrict__ out_u, int mode) {
  __shared__ __align__(16) unsigned char smem[32768];
  unsigned short* As = (unsigned short*)smem;
  unsigned short* Bs = As + 8192;
  unsigned int* tileT = (unsigned int*)smem;

  int L = blockIdx.x;
  int tid = threadIdx.x;

  int by = (int)((129.0 - sqrt(129.0 * 129.0 - 8.0 * (double)L)) * 0.5);
  while (64 * (by + 1) - ((by + 1) * by) / 2 <= L) by++;
  while (64 * by - (by * (by - 1)) / 2 > L) by--;
  int bx = by + (L - (64 * by - (by * (by - 1)) / 2));

  int wave = tid >> 6, lane = tid & 63;
  int wr = (wave >> 1) * 64, wc = (wave & 1) * 64;
  int m = lane & 15, quad = lane >> 4;

  f32x4 acc[4][4];
  #pragma unroll
  for (int i = 0; i < 4; i++)
    #pragma unroll
    for (int j = 0; j < 4; j++) acc[i][j] = (f32x4){0.f, 0.f, 0.f, 0.f};

  for (int kt = 0; kt < D / 64; kt++) {
    #pragma unroll
    for (int i = 0; i < 4; i++) {
      int f = i * 256 + tid;
      int r = f >> 3, c = f & 7;
      int cs = (c + r) & 7;
      size_t goff = (size_t)r * D + kt * 64 + cs * 8;
      gld16(G + (size_t)(by * 128) * D + goff, &As[f * 8]);
      gld16(G + (size_t)(bx * 128) * D + goff, &Bs[f * 8]);
    }
    if (L < 2048) {
      uint4 z = {0u, 0u, 0u, 0u};
      if (mode == 0) {
        size_t base = (size_t)L * 32768 + (size_t)kt * 4096;
        #pragma unroll
        for (int it2 = 0; it2 < 4; it2++)
          *(uint4*)(out_u + base + it2 * 1024 + tid * 4) = z;
      } else {
        #pragma unroll
        for (int it2 = 0; it2 < 2; it2++) {
          int g = L * 16384 + (kt * 2 + it2) * 1024 + tid * 4;
          int r = g >> 12, c = g & 4095;
          *(uint4*)(out_u + (size_t)r * ROWU + 4096 + c) = z;
        }
      }
    }
    __syncthreads();
    #pragma unroll
    for (int h = 0; h < 2; h++) {
      short8 fa[4], fb[4];
      #pragma unroll
      for (int ti = 0; ti < 4; ti++) {
        int row = wr + ti * 16 + m;
        int cc = ((h * 4 + quad) - row) & 7;
        fa[ti] = *(const short8*)&As[row * 64 + cc * 8];
      }
      #pragma unroll
      for (int tj = 0; tj < 4; tj++) {
        int row = wc + tj * 16 + m;
        int cc = ((h * 4 + quad) - row) & 7;
        fb[tj] = *(const short8*)&Bs[row * 64 + cc * 8];
      }
      #pragma unroll
      for (int ti = 0; ti < 4; ti++)
        #pragma unroll
        for (int tj = 0; tj < 4; tj++)
          acc[ti][tj] = __builtin_amdgcn_mfma_f32_16x16x32_bf16(
              fa[ti], fb[tj], acc[ti][tj], 0, 0, 0);
    }
    __syncthreads();
  }

  float lam = 1.f / (1.f + __expf(-lamw[0]));
  float T = temp[0];
  float oml = 1.f - lam;
  bool offdiag = (bx != by);

  #pragma unroll
  for (int ti = 0; ti < 4; ti++) {
    int gi0 = by * 128 + wr + ti * 16 + quad * 4;
    float xi[4], yi[4], sqi[4];
    #pragma unroll
    for (int r = 0; r < 4; r++) {
      int gi = gi0 + r;
      xi[r] = pos[2 * gi]; yi[r] = pos[2 * gi + 1]; sqi[r] = sqf[gi];
    }
    #pragma unroll
    for (int tj = 0; tj < 4; tj++) {
      int gj = bx * 128 + wc + tj * 16 + m;
      float xj = pos[2 * gj], yj = pos[2 * gj + 1], sj = sqf[gj];
      f32x4 c = acc[ti][tj];
      float sv[4];
      #pragma unroll
      for (int r = 0; r < 4; r++) {
        float d2 = fmaxf(sqi[r] + sj - 2.f * (xi[r] * xj + yi[r] * yj), 0.f);
        float sp = __expf(-d2 * (1.f / 5000.f));
        sv[r] = (lam * c[r] + oml * sp) * T;
      }
      int cpL = (wc + tj * 16 + m) >> 1;
      #pragma unroll
      for (int r = 0; r < 4; r++) {
        float pv = __shfl_xor(sv[r], 1, 64);
        if (!(lane & 1)) {
          int rowL = wr + ti * 16 + quad * 4 + r;
          tileT[swz(rowL, cpL)] = packh2(sv[r], pv);
        }
      }
    }
  }
  __syncthreads();

  #pragma unroll
  for (int it = 0; it < 8; it++) {
    int idx4 = it * 256 + tid;
    int row = idx4 >> 4, q = idx4 & 15;
    uint4 v = *(uint4*)&tileT[swz4(row, q)];
    *(uint4*)(filt + (size_t)(by * 128 + row) * fs + bx * 64 + q * 4) = v;
  }

  if (offdiag) {
    #pragma unroll
    for (int it = 0; it < 8; it++) {
      int idx4 = it * 256 + tid;
      int c = idx4 >> 4, q = idx4 & 15;
      unsigned int wv[4];
      #pragma unroll
      for (int d = 0; d < 4; d++) {
        int p = q * 4 + d;
        unsigned int lo = tileT[swz(2 * p, c >> 1)];
        unsigned int hi = tileT[swz(2 * p + 1, c >> 1)];
        unsigned int h0 = (c & 1) ? (lo >> 16) : (lo & 0xFFFFu);
        unsigned int h1 = (c & 1) ? (hi >> 16) : (hi & 0xFFFFu);
        wv[d] = h0 | (h1 << 16);
      }
      uint4 v; v.x = wv[0]; v.y = wv[1]; v.z = wv[2]; v.w = wv[3];
      *(uint4*)(filt + (size_t)(bx * 128 + c) * fs + by * 64 + q * 4) = v;
    }
  }
}

// ---------------------------------------------------------------------------
// K3: per-row exact top-20 — R12 version VERBATIM (proven 184 us, absmax 0.0):
// 256 thr/row, packed-fp16 filter regs, packed bsearch/prescreen, per-thread
// streamed np-exact recompute, wave0 selection.
// ---------------------------------------------------------------------------
__global__ __launch_bounds__(256, 4) void topk_kernel(
    const float* __restrict__ pos, const float* __restrict__ sqf,
    const float* __restrict__ lamw, const float* __restrict__ temp,
    const float* __restrict__ fn32,
    const unsigned int* __restrict__ filt, int fs,
    float* __restrict__ out, int doZero) {
  __shared__ float ai[D];
  __shared__ int   redi[2][4];
  __shared__ int   candIdx[CAND_CAP];
  __shared__ float candV[CAND_CAP];
  __shared__ int   selIdx[KSEL];
  __shared__ float selVal[KSEL];
  __shared__ int   cnt;

  int row = blockIdx.x, t = threadIdx.x;
  int lane = t & 63, wid = t >> 6;
  float* orow = out + (size_t)row * N;
  const uint4* fu4 = (const uint4*)(filt + (size_t)row * fs);
  const float* fn_i = fn32 + (size_t)row * D;

  unsigned int rv[16];
  #pragma unroll
  for (int q = 0; q < 4; q++) {
    uint4 u = fu4[t + 256 * q];
    rv[4 * q] = u.x; rv[4 * q + 1] = u.y; rv[4 * q + 2] = u.z; rv[4 * q + 3] = u.w;
  }
  for (int k = t; k < D; k += 256) ai[k] = fn_i[k];   // np-exact a_i
  if (t == 0) cnt = 0;
  __syncthreads();

  if (doZero) {
    float4 z4 = {0.f, 0.f, 0.f, 0.f};
    #pragma unroll
    for (int i = 0; i < 4; i++) *(float4*)&orow[4 * t + 1024 * i] = z4;
  }

  // --- packed binary search: count_ge >= 20, 12 iters on [-1, 1.5] ---
  float lo = -1.0f, hi = 1.5f;
  for (int it = 0; it < 12; it++) {
    float mid = 0.5f * (lo + hi);
    __half2 m2 = __float2half2_rn(mid);
    __half2 a2 = __float2half2_rn(0.f);
    #pragma unroll
    for (int r = 0; r < 16; r++)
      a2 = __hadd2(a2, __hge2(*(__half2*)&rv[r], m2));   // exact: counts <= 16
    int c = (int)(__low2float(a2) + __high2float(a2));
    #pragma unroll
    for (int off = 32; off > 0; off >>= 1) c += __shfl_down(c, off, 64);
    if (lane == 0) redi[it & 1][wid] = c;
    __syncthreads();
    int tot = redi[it & 1][0] + redi[it & 1][1] + redi[it & 1][2] + redi[it & 1][3];
    if (tot >= KSEL) lo = mid; else hi = mid;
  }

  // --- packed candidate sweep (R11/R12-proven margins) ---
  __half2 t2 = __float2half2_rn(lo - 3.7e-3f - 6e-4f);
  #pragma unroll
  for (int r = 0; r < 16; r++) {
    __half2 ge = __hge2(*(__half2*)&rv[r], t2);
    unsigned int g = *(unsigned int*)&ge;
    if (g) {
      int j0 = 8 * (t + 256 * (r >> 2)) + 2 * (r & 3);
      if (g & 0xFFFFu) {
        int p = atomicAdd(&cnt, 1);
        if (p < CAND_CAP) candIdx[p] = j0;
      }
      if (g >> 16) {
        int p = atomicAdd(&cnt, 1);
        if (p < CAND_CAP) candIdx[p] = j0 + 1;
      }
    }
  }
  __syncthreads();
  int ncand = min(cnt, CAND_CAP);

  // --- per-thread streamed np-exact recompute (FROZEN arithmetic) ---
  float lamf;
  { float e = (float)exp(-(double)lamw[0]); lamf = 1.0f / __fadd_rn(1.0f, e); }
  float omlf = __fadd_rn(1.0f, -lamf);
  float Tf = temp[0];
  float sq_i = sqf[row];
  float xi = pos[2 * row], yi = pos[2 * row + 1];

  if (t < ncand) {
    int j = candIdx[t];
    const float* fj = fn32 + (size_t)j * D;
    float accv = 0.0f;
    float4 buf[4], nxt[4];
    #pragma unroll
    for (int q = 0; q < 4; q++) buf[q] = *(const float4*)(fj + q * 4);
    for (int c16 = 0; c16 < 32; c16++) {
      if (c16 < 31) {
        #pragma unroll
        for (int q = 0; q < 4; q++)
          nxt[q] = *(const float4*)(fj + (c16 + 1) * 16 + q * 4);
      }
      #pragma unroll
      for (int q = 0; q < 4; q++) {
        float4 a4 = *(const float4*)&ai[c16 * 16 + q * 4];   // LDS broadcast
        accv = __fmaf_rn(a4.x, buf[q].x, accv);              // frozen k-order
        accv = __fmaf_rn(a4.y, buf[q].y, accv);
        accv = __fmaf_rn(a4.z, buf[q].z, accv);
        accv = __fmaf_rn(a4.w, buf[q].w, accv);
      }
      #pragma unroll
      for (int q = 0; q < 4; q++) buf[q] = nxt[q];
    }
    float xj = pos[2 * j], yj = pos[2 * j + 1];
    float dot2 = __fmaf_rn(yi, yj, __fmul_rn(xi, xj));
    float Ssum = __fadd_rn(sq_i, sqf[j]);
    float d2 = fmaxf(__fadd_rn(Ssum, -__fmul_rn(2.0f, dot2)), 0.0f);
    float arg = (-d2) / 5000.0f;
    float sp = (float)exp((double)arg);
    float u = __fmul_rn(__fadd_rn(__fmul_rn(lamf, accv), __fmul_rn(omlf, sp)), Tf);
    float e = (float)exp(-(double)u);
    candV[t] = 1.0f / __fadd_rn(1.0f, e);
  }
  __syncthreads();

  // --- selection: wave0 only, value desc, index asc (lax.top_k ties) ---
  if (t < 64) {
    for (int s = 0; s < KSEL; s++) {
      float bu = -1.0f; int bj = N, bs = 0;
      for (int c = t; c < ncand; c += 64) {
        float v = candV[c]; int j = candIdx[c];
        if (v > bu || (v == bu && j < bj)) { bu = v; bj = j; bs = c; }
      }
      #pragma unroll
      for (int off = 32; off > 0; off >>= 1) {
        float ov = __shfl_down(bu, off, 64);
        int   oj = __shfl_down(bj, off, 64);
        int   os = __shfl_down(bs, off, 64);
        if (ov > bu || (ov == bu && oj < bj)) { bu = ov; bj = oj; bs = os; }
      }
      if (t == 0) { selIdx[s] = bj; selVal[s] = bu; candV[bs] = -1.0f; }
      __builtin_amdgcn_s_waitcnt(0);
    }
  }
  __syncthreads();
  if (t < KSEL) orow[selIdx[t]] = selVal[t];
}

extern "C" void kernel_launch(void* const* d_in, const int* in_sizes, int n_in,
                              void* d_out, int out_size, void* d_ws, size_t ws_size,
                              hipStream_t stream) {
  const float* feat = (const float*)d_in[0];
  const float* pos  = (const float*)d_in[1];
  const float* lamw = (const float*)d_in[2];
  const float* temp = (const float*)d_in[3];
  float* out = (float*)d_out;
  unsigned int* out_u = (unsigned int*)d_out;

  float* normf = (float*)d_ws;
  float* sqf   = normf + N;
  float* fn32  = sqf + N;
  unsigned short* fnbf = (unsigned short*)(fn32 + (size_t)N * D);
  unsigned int* filtA = (unsigned int*)(fnbf + (size_t)N * D);
  size_t needA = (size_t)2 * N * 4 + (size_t)N * D * 4 + (size_t)N * D * 2 +
                 (size_t)N * FS_A * 4;

  prep_kernel<<<N / 4, 256, 0, stream>>>(feat, pos, lamw, normf, sqf,
                                         fn32, fnbf, out);
  if (ws_size >= needA) {
    adj_kernel<<<2080, 256, 0, stream>>>(fnbf, pos, sqf, lamw, temp,
                                         filtA, FS_A, out_u, 0);
    topk_kernel<<<N, 256, 0, stream>>>(pos, sqf, lamw, temp, fn32,
                                       filtA, FS_A, out, 0);
  } else {
    adj_kernel<<<2080, 256, 0, stream>>>(fnbf, pos, sqf, lamw, temp,
                                         out_u, ROWU, out_u, 1);
    topk_kernel<<<N, 256, 0, stream>>>(pos, sqf, lamw, temp, fn32,
                                       out_u, ROWU, out, 1);
  }
}